// Round 4
// baseline (10908.636 us; speedup 1.0000x reference)
//
#include <hip/hip_runtime.h>
#include <float.h>

#define NB 64
#define HD 1024
#define H3 3072
#define NC6 6144
#define NV 32000
#define TSTEPS 32
#define LBLK 500        // logits blocks (64 cols each)
#define GKS 4           // gates K-split

__device__ __forceinline__ float sigmoidf_(float x) {
    return 1.0f / (1.0f + expf(-x));
}

__device__ __forceinline__ float dot4(float4 h, float4 w, float a) {
    return fmaf(h.w, w.w, fmaf(h.z, w.z, fmaf(h.y, w.y, fmaf(h.x, w.x, a))));
}

// ---------------- init: ht4 = [zs|cs]^T, xt4 = emb[SOS=1]^T ----------------
__global__ __launch_bounds__(256) void init_kernel(
    const float* __restrict__ zs, const float* __restrict__ cs,
    const float* __restrict__ emb,
    float4* __restrict__ ht4, float4* __restrict__ xt4)
{
    int b = blockIdx.x;
    int kg = threadIdx.x;
    int j = kg * 4;
    float4 v;
    if (j < 512) v = *(const float4*)&zs[b * 512 + j];
    else         v = *(const float4*)&cs[b * 512 + (j - 512)];
    ht4[kg * NB + b] = v;
    xt4[kg * NB + b] = *(const float4*)&emb[HD + j];  // SOS = 1
}

// ---------------- logits: no-LDS GEMV + per-block argmax ----------------
// 500 blocks x 512 thr. wave w: cols c0=blk*64+w*8 .. +7; lane = batch.
// W loads wave-uniform (1 transaction); ht4 loads lane-coalesced (L2-hot).
__global__ __launch_bounds__(512) void logits_gemv(
    const float4* __restrict__ ht4, const float* __restrict__ Wout,
    const float* __restrict__ bout,
    float* __restrict__ bval, int* __restrict__ bidx)
{
    int tid = threadIdx.x, wid = tid >> 6, lane = tid & 63;
    int c0 = blockIdx.x * 64 + wid * 8;
    const float* __restrict__ wb = Wout + (size_t)c0 * HD;

    float4 hbuf[4];
    #pragma unroll
    for (int i = 0; i < 4; ++i) hbuf[i] = ht4[i * NB + lane];

    float acc[8] = {};
    for (int kt = 0; kt < 64; ++kt) {
        // batch-issue this kt's W (8 rows x 64B contiguous each)
        float4 wk[8][4];
        #pragma unroll
        for (int r = 0; r < 8; ++r)
            #pragma unroll
            for (int i = 0; i < 4; ++i)
                wk[r][i] = *(const float4*)&wb[r * HD + kt * 16 + i * 4];
        float4 hcur[4];
        #pragma unroll
        for (int i = 0; i < 4; ++i) hcur[i] = hbuf[i];
        if (kt < 63) {
            #pragma unroll
            for (int i = 0; i < 4; ++i) hbuf[i] = ht4[((kt + 1) * 4 + i) * NB + lane];
        }
        #pragma unroll
        for (int i = 0; i < 4; ++i)
            #pragma unroll
            for (int r = 0; r < 8; ++r)
                acc[r] = dot4(hcur[i], wk[r][i], acc[r]);
    }

    // bias + per-lane argmax over this wave's 8 cols (ascending -> first-max)
    float bv = acc[0] + bout[c0];
    int   bi = c0;
    #pragma unroll
    for (int r = 1; r < 8; ++r) {
        float v = acc[r] + bout[c0 + r];
        if (v > bv) { bv = v; bi = c0 + r; }
    }
    __shared__ float sv[8][NB];
    __shared__ int   si[8][NB];
    sv[wid][lane] = bv;
    si[wid][lane] = bi;
    __syncthreads();
    if (wid == 0) {
        float v0 = sv[0][lane]; int i0 = si[0][lane];
        #pragma unroll
        for (int s = 1; s < 8; ++s) {
            float v = sv[s][lane];
            if (v > v0) { v0 = v; i0 = si[s][lane]; }   // slots ascend in col
        }
        bval[(size_t)lane * LBLK + blockIdx.x] = v0;
        bidx[(size_t)lane * LBLK + blockIdx.x] = i0;
    }
}

// ---------------- gates: no-LDS GEMV, K-split 4, gpart[ks][b][6144] ----------------
// 384 blocks x 512 thr. cg = blk>>2 (64 cols), ks = blk&3 (256-k slice).
__global__ __launch_bounds__(512) void gates_gemv(
    const float4* __restrict__ xt4, const float4* __restrict__ ht4,
    const float* __restrict__ Wih, const float* __restrict__ Whh,
    float* __restrict__ gpart)
{
    int cg = blockIdx.x >> 2;
    int ks = blockIdx.x & 3;
    int tid = threadIdx.x, wid = tid >> 6, lane = tid & 63;
    int c0 = cg * 64 + wid * 8;            // 0..6143
    bool isH = c0 >= H3;
    const float4* __restrict__ T4 = isH ? ht4 : xt4;
    const float* __restrict__ W   = isH ? Whh : Wih;
    int wc0 = c0 - (isH ? H3 : 0);
    const float* __restrict__ wb = W + (size_t)wc0 * HD + ks * 256;
    int kgbase = ks * 64;

    float4 hbuf[4];
    #pragma unroll
    for (int i = 0; i < 4; ++i) hbuf[i] = T4[(kgbase + i) * NB + lane];

    float acc[8] = {};
    for (int kt = 0; kt < 16; ++kt) {
        float4 wk[8][4];
        #pragma unroll
        for (int r = 0; r < 8; ++r)
            #pragma unroll
            for (int i = 0; i < 4; ++i)
                wk[r][i] = *(const float4*)&wb[r * HD + kt * 16 + i * 4];
        float4 hcur[4];
        #pragma unroll
        for (int i = 0; i < 4; ++i) hcur[i] = hbuf[i];
        if (kt < 15) {
            #pragma unroll
            for (int i = 0; i < 4; ++i)
                hbuf[i] = T4[(kgbase + (kt + 1) * 4 + i) * NB + lane];
        }
        #pragma unroll
        for (int i = 0; i < 4; ++i)
            #pragma unroll
            for (int r = 0; r < 8; ++r)
                acc[r] = dot4(hcur[i], wk[r][i], acc[r]);
    }
    float* g = gpart + (size_t)(ks * NB + lane) * NC6 + c0;
    *(float4*)(g)     = make_float4(acc[0], acc[1], acc[2], acc[3]);
    *(float4*)(g + 4) = make_float4(acc[4], acc[5], acc[6], acc[7]);
}

// ---------------- GRU gate fusion: ht4 = (1-z)*n + z*ht4 ----------------
__global__ __launch_bounds__(256) void gru_fuse(
    const float* __restrict__ gpart,
    const float* __restrict__ bih, const float* __restrict__ bhh,
    float4* __restrict__ ht4)
{
    int b = blockIdx.x;
    int kg = threadIdx.x;
    int j0 = kg * 4;
    float4 ir = {}, iz = {}, in_ = {}, hr = {}, hz = {}, hn = {};
    #pragma unroll
    for (int ks = 0; ks < GKS; ++ks) {
        const float* g = gpart + (size_t)(ks * NB + b) * NC6;
        float4 a;
        a = *(const float4*)&g[j0];             ir.x+=a.x; ir.y+=a.y; ir.z+=a.z; ir.w+=a.w;
        a = *(const float4*)&g[HD + j0];        iz.x+=a.x; iz.y+=a.y; iz.z+=a.z; iz.w+=a.w;
        a = *(const float4*)&g[2*HD + j0];      in_.x+=a.x; in_.y+=a.y; in_.z+=a.z; in_.w+=a.w;
        a = *(const float4*)&g[H3 + j0];        hr.x+=a.x; hr.y+=a.y; hr.z+=a.z; hr.w+=a.w;
        a = *(const float4*)&g[H3 + HD + j0];   hz.x+=a.x; hz.y+=a.y; hz.z+=a.z; hz.w+=a.w;
        a = *(const float4*)&g[H3 + 2*HD + j0]; hn.x+=a.x; hn.y+=a.y; hn.z+=a.z; hn.w+=a.w;
    }
    float4 vbi0 = *(const float4*)&bih[j0];
    float4 vbi1 = *(const float4*)&bih[HD + j0];
    float4 vbi2 = *(const float4*)&bih[2*HD + j0];
    float4 vbh0 = *(const float4*)&bhh[j0];
    float4 vbh1 = *(const float4*)&bhh[HD + j0];
    float4 vbh2 = *(const float4*)&bhh[2*HD + j0];
    float4 hv = ht4[kg * NB + b];
    float irv[4] = {ir.x+vbi0.x, ir.y+vbi0.y, ir.z+vbi0.z, ir.w+vbi0.w};
    float izv[4] = {iz.x+vbi1.x, iz.y+vbi1.y, iz.z+vbi1.z, iz.w+vbi1.w};
    float inv[4] = {in_.x+vbi2.x, in_.y+vbi2.y, in_.z+vbi2.z, in_.w+vbi2.w};
    float hrv[4] = {hr.x+vbh0.x, hr.y+vbh0.y, hr.z+vbh0.z, hr.w+vbh0.w};
    float hzv[4] = {hz.x+vbh1.x, hz.y+vbh1.y, hz.z+vbh1.z, hz.w+vbh1.w};
    float hnv[4] = {hn.x+vbh2.x, hn.y+vbh2.y, hn.z+vbh2.z, hn.w+vbh2.w};
    float hvv[4] = {hv.x, hv.y, hv.z, hv.w};
    float o[4];
    #pragma unroll
    for (int u = 0; u < 4; ++u) {
        float r = sigmoidf_(irv[u] + hrv[u]);
        float z = sigmoidf_(izv[u] + hzv[u]);
        float n = tanhf(inv[u] + r * hnv[u]);
        o[u] = (1.0f - z) * n + z * hvv[u];
    }
    ht4[kg * NB + b] = make_float4(o[0], o[1], o[2], o[3]);
}

// ---------------- argmax reduce across 500 blocks + embedding gather ----------------
__global__ __launch_bounds__(512) void argmax_reduce_gather(
    const float* __restrict__ bval, const int* __restrict__ bidx,
    const float* __restrict__ emb, int* __restrict__ resps, int t,
    float4* __restrict__ xt4)
{
    int b = blockIdx.x;
    int tid = threadIdx.x;
    float bv = -FLT_MAX; int bi = 0x7fffffff;
    if (tid < LBLK) { bv = bval[(size_t)b * LBLK + tid]; bi = bidx[(size_t)b * LBLK + tid]; }
    for (int off = 32; off > 0; off >>= 1) {
        float ov = __shfl_down(bv, off);
        int   oi = __shfl_down(bi, off);
        if (ov > bv || (ov == bv && oi < bi)) { bv = ov; bi = oi; }
    }
    __shared__ float sv[8];
    __shared__ int   si[8];
    __shared__ int   stok;
    int wid = tid >> 6;
    if ((tid & 63) == 0) { sv[wid] = bv; si[wid] = bi; }
    __syncthreads();
    if (tid == 0) {
        bv = sv[0]; bi = si[0];
        #pragma unroll
        for (int w = 1; w < 8; ++w)
            if (sv[w] > bv || (sv[w] == bv && si[w] < bi)) { bv = sv[w]; bi = si[w]; }
        stok = bi;
        resps[b * TSTEPS + t] = bi;
    }
    __syncthreads();
    if (tid < 256) {
        int tok = stok;
        xt4[tid * NB + b] = *(const float4*)&emb[(size_t)tok * HD + tid * 4];
    }
}

// ---------------- resp_lens ----------------
__global__ void resp_lens_kernel(const int* __restrict__ resps, int* __restrict__ lens)
{
    int b = threadIdx.x;
    if (b >= NB) return;
    int len = TSTEPS + 1;
    for (int t = TSTEPS - 1; t >= 0; t--)
        if (resps[b * TSTEPS + t] == 2) len = t + 1;
    lens[b] = len;
}

extern "C" void kernel_launch(void* const* d_in, const int* in_sizes, int n_in,
                              void* d_out, int out_size, void* d_ws, size_t ws_size,
                              hipStream_t stream) {
    const float* zs   = (const float*)d_in[0];
    const float* cs   = (const float*)d_in[1];
    const float* emb  = (const float*)d_in[2];
    const float* Wih  = (const float*)d_in[3];
    const float* Whh  = (const float*)d_in[4];
    const float* bih  = (const float*)d_in[5];
    const float* bhh  = (const float*)d_in[6];
    const float* Wout = (const float*)d_in[7];
    const float* bout = (const float*)d_in[8];
    int* out = (int*)d_out;  // [64*32 resps][64 lens], int32

    char* ws = (char*)d_ws;
    float4* xt4  = (float4*)ws; ws += (size_t)256 * NB * 16;          // 256 KB
    float4* ht4  = (float4*)ws; ws += (size_t)256 * NB * 16;          // 256 KB
    float*  gpart = (float*)ws; ws += (size_t)GKS * NB * NC6 * 4;     // 6.3 MB
    float*  bval = (float*)ws;  ws += (size_t)NB * LBLK * 4;          // 128 KB
    int*    bidx = (int*)ws;    ws += (size_t)NB * LBLK * 4;          // 128 KB

    init_kernel<<<NB, 256, 0, stream>>>(zs, cs, emb, ht4, xt4);
    for (int t = 0; t < TSTEPS; t++) {
        gates_gemv<<<96 * GKS, 512, 0, stream>>>(xt4, ht4, Wih, Whh, gpart);
        gru_fuse<<<NB, 256, 0, stream>>>(gpart, bih, bhh, ht4);
        logits_gemv<<<LBLK, 512, 0, stream>>>(ht4, Wout, bout, bval, bidx);
        argmax_reduce_gather<<<NB, 512, 0, stream>>>(bval, bidx, emb, out, t, xt4);
    }
    resp_lens_kernel<<<1, 64, 0, stream>>>(out, out + NB * TSTEPS);
}